// Round 18
// baseline (19.367 us; speedup 1.0000x reference)
//
#include <hip/hip_runtime.h>
#include <hip/hip_bf16.h>

// Problem constants: B=8, G=2048, K=32, N=6, C=64; fourier_B is (7,32)
// out: (B, 128, G) float32
//
// Algebraic simplifications (validated):
//  1) up/down == mean_k(knn_f) since e_x is constant over k, so
//     kl_raw = 2*mean_k(sin^5/cos^5(2*pi*x)).
//  2) x = fB . [p, p x n, p.n] is linear in p:
//     x = e0*p0 + e1*p1 + e2*p2 with per-channel e precomputed from fB and n.
//  3) kl/||kl|| is scale-invariant -> 1/16 mean factor dropped (r15 validated).
//
// Round 18 (on r17's 19.34us): async knn staging via global_load_lds(16B).
//  - one instruction stages all 64 records/wave: per-lane source
//    row + jj*24 + 8 (floats 2..5 -> p in .y/.z/.w; jj=31 ends exactly at the
//    row boundary, no OOB), LDS dest = uniform base + lane*16.
//  - removes 3 scalar loads + VGPR round-trip + ds_write + lgkm drain from
//    every wave's serial head; wait is a single vmcnt(0) before the k-loop.
//  - norms/e-vectors still hoisted to overlap the staging latency.

#if __has_builtin(__builtin_amdgcn_fractf)
  #define FRACT(x) __builtin_amdgcn_fractf(x)
#else
  #define FRACT(x) ((x) - floorf(x))
#endif

typedef float f2v __attribute__((ext_vector_type(2)));

__device__ __forceinline__ float rlanef(float v, int l) {
    return __int_as_float(__builtin_amdgcn_readlane(__float_as_int(v), l));
}

// Full-wave (64-lane) f32 sum via DPP; result wave-uniform.
__device__ __forceinline__ float wave_sum64(float v) {
    float s = v;
    s += __int_as_float(__builtin_amdgcn_update_dpp(
            0, __float_as_int(s), 0x111, 0xf, 0xf, true));  // row_shr:1
    s += __int_as_float(__builtin_amdgcn_update_dpp(
            0, __float_as_int(s), 0x112, 0xf, 0xf, true));  // row_shr:2
    s += __int_as_float(__builtin_amdgcn_update_dpp(
            0, __float_as_int(s), 0x114, 0xf, 0xf, true));  // row_shr:4
    s += __int_as_float(__builtin_amdgcn_update_dpp(
            0, __float_as_int(s), 0x118, 0xf, 0xf, true));  // row_shr:8
    s += __int_as_float(__builtin_amdgcn_update_dpp(
            0, __float_as_int(s), 0x142, 0xf, 0xf, true));  // row_bcast:15
    s += __int_as_float(__builtin_amdgcn_update_dpp(
            0, __float_as_int(s), 0x143, 0xf, 0xf, true));  // row_bcast:31
    return rlanef(s, 63);
}

__global__ __launch_bounds__(256, 8) void line_pass1(
    const float* __restrict__ lc_x,     // (B,G,64)
    const float* __restrict__ knn_x,    // (B,G,32,6)
    const float* __restrict__ fB,       // (7,32)
    float* __restrict__ out)            // (B,128,G)
{
    const int wave = threadIdx.x >> 6;
    const int lane = threadIdx.x & 63;
    const int half = lane >> 5;                 // staging: which bg; loop: k parity
    const int jj   = lane & 31;                 // channel, and gather-k
    // bijective XCD swizzle: 2048 blocks, 8 XCDs, 256 blocks each
    const int sbid = (blockIdx.x & 7) * 256 + (blockIdx.x >> 3);
    const int bg0  = sbid * 8;                  // 8 consecutive bg per block
    const int b    = bg0 >> 11;
    const int g0   = bg0 & 2047;                // 8-aligned, never crosses b

    // pbuf[wave][half*32+k] = float4 with p in .y/.z/.w (float .x unused)
    __shared__ __align__(16) float4 pbuf[4][64];
    __shared__ float klbuf[128][9];                  // [channel][col], odd pad

    const int bgw = bg0 + wave * 2;

    // ---- issue lc loads, then async knn->LDS staging (vmcnt-tracked)
    const float myv0 = lc_x[(size_t)bgw * 64 + lane];
    const float myv1 = lc_x[(size_t)(bgw + 1) * 64 + lane];
#if __has_builtin(__builtin_amdgcn_global_load_lds)
    {
        // per-lane source: record (bg=bgw+half, k=jj), floats 2..5 (16B, in-bounds)
        const float* src = knn_x + (size_t)(bgw + half) * 192 + jj * 6 + 2;
        __builtin_amdgcn_global_load_lds((const __attribute__((address_space(1))) void*)src,
                                         (__attribute__((address_space(3))) void*)&pbuf[wave][0],
                                         16, 0, 0);
    }
#else
    {
        const float* kp = knn_x + (size_t)(bgw + half) * 192 + jj * 6;
        pbuf[wave][half * 32 + jj] = make_float4(0.0f, kp[3], kp[4], kp[5]);
    }
#endif

    // fourier_B column for this lane's channel
    const float fb0 = fB[0*32 + jj];
    const float fb1 = fB[1*32 + jj];
    const float fb2 = fB[2*32 + jj];
    const float fb3 = fB[3*32 + jj];
    const float fb4 = fB[4*32 + jj];
    const float fb5 = fB[5*32 + jj];
    const float fb6 = fB[6*32 + jj];

    // ---- norms + e-vectors for BOTH bg while staging is in flight
    const float nA0 = rlanef(myv0, 3), nA1 = rlanef(myv0, 4), nA2 = rlanef(myv0, 5);
    const float nB0 = rlanef(myv1, 3), nB1 = rlanef(myv1, 4), nB2 = rlanef(myv1, 5);

    const float ssA = wave_sum64(myv0 * myv0);
    const float ssB = wave_sum64(myv1 * myv1);
    klbuf[64 + lane][wave * 2 + 0] = myv0 * __builtin_amdgcn_rsqf(ssA);
    klbuf[64 + lane][wave * 2 + 1] = myv1 * __builtin_amdgcn_rsqf(ssB);

    const float e0A = fmaf(fb6, nA0, fmaf(fb5,  nA1, fmaf(fb4, -nA2, fb0)));
    const float e1A = fmaf(fb6, nA1, fmaf(fb5, -nA0, fmaf(fb3,  nA2, fb1)));
    const float e2A = fmaf(fb6, nA2, fmaf(fb4,  nA0, fmaf(fb3, -nA1, fb2)));
    const float e0B = fmaf(fb6, nB0, fmaf(fb5,  nB1, fmaf(fb4, -nB2, fb0)));
    const float e1B = fmaf(fb6, nB1, fmaf(fb5, -nB0, fmaf(fb3,  nB2, fb1)));
    const float e2B = fmaf(fb6, nB2, fmaf(fb4,  nB0, fmaf(fb3, -nB1, fb2)));

    // staging complete (global_load_lds is vmcnt-tracked); same-wave consumer
    asm volatile("s_waitcnt vmcnt(0) lgkmcnt(0)" ::: "memory");
    __builtin_amdgcn_sched_barrier(0);

    // ---- fused dual-bg k-loop: k = 2*t + half for each bg; p = (.y,.z,.w)
    f2v accA0 = {0.f, 0.f}, accA1 = {0.f, 0.f};
    f2v accB0 = {0.f, 0.f}, accB1 = {0.f, 0.f};
    const float4* pa = &pbuf[wave][half];           // bg 0 records
    const float4* pb = &pbuf[wave][32 + half];      // bg 1 records
    #pragma unroll
    for (int t = 0; t < 16; ++t) {
        const float4 p = pa[2 * t];                 // uniform b128 broadcast
        const float4 q = pb[2 * t];
        const float xA = fmaf(e2A, p.w, fmaf(e1A, p.z, e0A * p.y));
        const float xB = fmaf(e2B, q.w, fmaf(e1B, q.z, e0B * q.y));
        const float tA = FRACT(xA);
        const float tB = FRACT(xB);
        f2v scA; scA.x = __builtin_amdgcn_sinf(tA); scA.y = __builtin_amdgcn_cosf(tA);
        f2v scB; scB.x = __builtin_amdgcn_sinf(tB); scB.y = __builtin_amdgcn_cosf(tB);
        const f2v sA2 = scA * scA, sB2 = scB * scB;     // v_pk_mul_f32
        const f2v sA4 = sA2 * sA2, sB4 = sB2 * sB2;
        if (t & 1) { accA1 += sA4 * scA; accB1 += sB4 * scB; }  // v_pk_fma_f32
        else       { accA0 += sA4 * scA; accB0 += sB4 * scB; }
    }
    const f2v aA = accA0 + accA1;       // {sin-sum, cos-sum} for this k-parity
    const f2v aB = accB0 + accB1;

    // merge even-k / odd-k halves across the lane32 boundary
    const float sA = aA.x + __shfl_xor(aA.x, 32, 64);
    const float cA = aA.y + __shfl_xor(aA.y, 32, 64);
    const float sB = aB.x + __shfl_xor(aB.x, 32, 64);
    const float cB = aB.y + __shfl_xor(aB.y, 32, 64);
    klbuf[lane][wave * 2 + 0] = half ? cA : sA;   // unscaled (norm cancels)
    klbuf[lane][wave * 2 + 1] = half ? cB : sB;

    __syncthreads();

    // cooperative coalesced store: thread t -> row c=t>>1, cols (t&1)*4..+3
    const int c  = threadIdx.x >> 1;
    const int j0 = (threadIdx.x & 1) * 4;
    const float4 o = make_float4(klbuf[c][j0], klbuf[c][j0+1],
                                 klbuf[c][j0+2], klbuf[c][j0+3]);
    *(float4*)(out + ((size_t)b * 128 + c) * 2048 + g0 + j0) = o;
}

__global__ __launch_bounds__(256) void line_pass2(float* __restrict__ out)
{
    const int b = blockIdx.x >> 6;   // 0..7
    const int c = blockIdx.x & 63;   // 0..63
    float4*       kl = (float4*)(out + ((size_t)b * 128 + c) * 2048);
    const float4* ll = (const float4*)(out + ((size_t)b * 128 + 64 + c) * 2048);
    const int t = threadIdx.x;

    // issue ALL loads before the reduction so HBM latencies overlap
    const float4 v0 = kl[t];
    const float4 v1 = kl[t + 256];
    const float4 l0 = ll[t];
    const float4 l1 = ll[t + 256];

    float ss = v0.x*v0.x + v0.y*v0.y + v0.z*v0.z + v0.w*v0.w
             + v1.x*v1.x + v1.y*v1.y + v1.z*v1.z + v1.w*v1.w;
    #pragma unroll
    for (int off = 32; off; off >>= 1) ss += __shfl_xor(ss, off, 64);

    __shared__ float wsum[4];
    if ((t & 63) == 0) wsum[t >> 6] = ss;
    __syncthreads();
    const float tot = wsum[0] + wsum[1] + wsum[2] + wsum[3];
    const float rn  = __builtin_amdgcn_rsqf(tot);

    kl[t]       = make_float4(fmaf(v0.x, rn, -l0.x), fmaf(v0.y, rn, -l0.y),
                              fmaf(v0.z, rn, -l0.z), fmaf(v0.w, rn, -l0.w));
    kl[t + 256] = make_float4(fmaf(v1.x, rn, -l1.x), fmaf(v1.y, rn, -l1.y),
                              fmaf(v1.z, rn, -l1.z), fmaf(v1.w, rn, -l1.w));
}

extern "C" void kernel_launch(void* const* d_in, const int* in_sizes, int n_in,
                              void* d_out, int out_size, void* d_ws, size_t ws_size,
                              hipStream_t stream) {
    const float* lc_x  = (const float*)d_in[0];   // 8*2048*64
    const float* knn_x = (const float*)d_in[1];   // 8*2048*32*6
    const float* fB    = (const float*)d_in[2];   // 7*32
    float* out = (float*)d_out;                   // 8*128*2048

    line_pass1<<<2048, 256, 0, stream>>>(lc_x, knn_x, fB, out);
    line_pass2<<<512, 256, 0, stream>>>(out);
}